// Round 14
// baseline (257.953 us; speedup 1.0000x reference)
//
#include <hip/hip_runtime.h>
#include <hip/hip_bf16.h>
#include <math.h>

#define NP 512
#define NW 3584
#define NT 4096
#define FIN 256
#define H1 8
#define O1 32
#define H2 8
#define O2 256
#define NEG 0.2f

typedef __attribute__((ext_vector_type(8))) short bf16x8;
typedef __attribute__((ext_vector_type(4))) float f32x4;
typedef unsigned long long u64;

__device__ __forceinline__ unsigned short f2bf(float f) {
    unsigned u = __float_as_uint(f);
    unsigned r = (u + 0x7FFF + ((u >> 16) & 1)) >> 16;
    return (unsigned short)r;
}
__device__ __forceinline__ float rflf(float x) {
    return __uint_as_float(__builtin_amdgcn_readfirstlane(__float_as_uint(x)));
}

// ===== fused prep: conv_word | gat1_hp | conv_w2 | pack_adj(u32-T) | cvec | wtab
// grid = 896 + 256 + 128 + 896 + 1 + 8 = 2185 blocks of 256
__global__ __launch_bounds__(256) void k_prep(
    const float* __restrict__ wf, const float* __restrict__ pf,
    const float* __restrict__ w1, const float* __restrict__ a_src1,
    const float* __restrict__ a_dst1, const float* __restrict__ w2,
    const float* __restrict__ b2, const float* __restrict__ W_fc,
    const float* __restrict__ a_src2, const float* __restrict__ a_dst2,
    const int* __restrict__ wp_adj,
    unsigned short* __restrict__ abf, unsigned short* __restrict__ btbf,
    float* __restrict__ hp1, float* __restrict__ ss1, float* __restrict__ sd1,
    unsigned* __restrict__ maskT, float* __restrict__ cvec,
    float* __restrict__ wtab)
{
    __shared__ float tile[64][65];
    __shared__ float feat[2][FIN];
    __shared__ float red[4][5];
    int blk = blockIdx.x;
    int t = threadIdx.x;
    if (blk < 896) {
        int idx4 = blk * 256 + t;
        float4 x = ((const float4*)wf)[idx4];
        ushort4 y;
        y.x = f2bf(x.x); y.y = f2bf(x.y); y.z = f2bf(x.z); y.w = f2bf(x.w);
        ((ushort4*)abf)[idx4] = y;
    } else if (blk < 1152) {
        int n0 = (blk - 896) * 2;
        feat[0][t] = pf[n0 * FIN + t];
        feat[1][t] = pf[(n0 + 1) * FIN + t];
        __syncthreads();
        int h = t >> 5, o = t & 31;
        float acc0 = 0.f, acc1 = 0.f;
        const float* wcol = w1 + h * FIN * O1 + o;
        #pragma unroll 4
        for (int f = 0; f < FIN; f++) {
            float w = wcol[f * O1];
            acc0 += feat[0][f] * w;
            acc1 += feat[1][f] * w;
        }
        hp1[n0 * 256 + t] = acc0;
        hp1[(n0 + 1) * 256 + t] = acc1;
        float as = a_src1[h * O1 + o];
        float ad = a_dst1[h * O1 + o];
        float accs[2] = {acc0, acc1};
        #pragma unroll
        for (int i = 0; i < 2; i++) {
            float th = tanhf(accs[i]);
            float vs = th * as, vd = th * ad;
            #pragma unroll
            for (int off = 1; off < 32; off <<= 1) {
                vs += __shfl_xor(vs, off);
                vd += __shfl_xor(vd, off);
            }
            if (o == 0) { ss1[h * NP + n0 + i] = vs; sd1[h * NP + n0 + i] = vd; }
        }
    } else if (blk < 1280) {
        int blk2 = blk - 1152;
        int h = blk2 >> 4;
        int f0 = ((blk2 >> 2) & 3) * 64;
        int o0 = (blk2 & 3) * 64;
        #pragma unroll
        for (int rr = 0; rr < 16; rr++) {
            int f = rr * 4 + (t >> 6);
            int o = t & 63;
            tile[f][o] = w2[((size_t)(h * FIN + f0 + f)) * O2 + o0 + o];
        }
        __syncthreads();
        #pragma unroll
        for (int rr = 0; rr < 16; rr++) {
            int o = rr * 4 + (t >> 6);
            int f = t & 63;
            btbf[((size_t)(h * O2 + o0 + o)) * FIN + f0 + f] = f2bf(tile[f][o]);
        }
    } else if (blk < 2176) {
        // pack_adj -> u32 transposed: maskT[word(128)][row(3584)]
        int w = t >> 6, l = t & 63;
        int r = (blk - 1280) * 4 + w;
        const int4* row = (const int4*)(wp_adj + (size_t)r * NT);
        for (int c4 = 0; c4 < 16; c4++) {
            int4 x = row[c4 * 64 + l];
            u64 nib = (u64)((x.x != 0 ? 1 : 0) | (x.y != 0 ? 2 : 0) |
                            (x.z != 0 ? 4 : 0) | (x.w != 0 ? 8 : 0));
            u64 v = nib << (4 * (l & 15));
            v |= __shfl_xor(v, 1);
            v |= __shfl_xor(v, 2);
            v |= __shfl_xor(v, 4);
            v |= __shfl_xor(v, 8);
            if ((l & 15) == 0) {
                int qw = c4 * 4 + (l >> 4);
                maskT[(size_t)(2 * qw) * NW + r]     = (unsigned)v;
                maskT[(size_t)(2 * qw + 1) * NW + r] = (unsigned)(v >> 32);
            }
        }
    } else if (blk == 2176) {
        float v[5];
        #pragma unroll
        for (int j = 0; j < 5; j++) v[j] = b2[t] * W_fc[t * 5 + j];
        #pragma unroll
        for (int off = 1; off < 64; off <<= 1)
            #pragma unroll
            for (int j = 0; j < 5; j++) v[j] += __shfl_xor(v[j], off);
        int w = t >> 6, l = t & 63;
        if (l == 0) { for (int j = 0; j < 5; j++) red[w][j] = v[j]; }
        __syncthreads();
        if (t == 0)
            for (int j = 0; j < 5; j++) cvec[j] = red[0][j] + red[1][j] + red[2][j] + red[3][j];
    } else {
        int h = blk - 2177;
        int o = t;
        float* dst = wtab + ((size_t)h * O2 + o) * 8;
        float4 d0 = {a_src2[h * O2 + o], a_dst2[h * O2 + o], W_fc[o * 5], W_fc[o * 5 + 1]};
        float4 d1 = {W_fc[o * 5 + 2], W_fc[o * 5 + 3], W_fc[o * 5 + 4], 0.f};
        *(float4*)dst = d0;
        *(float4*)(dst + 4) = d1;
    }
}

// ---- GAT1 attention: m-split x2 -> grid 1024 (n x mh), partial den/acc out ----
__global__ __launch_bounds__(256) void k_gat1_attn(
    const int* __restrict__ adj, const float* __restrict__ hp1,
    const float* __restrict__ ss1, const float* __restrict__ sd1,
    float* __restrict__ g1acc, float* __restrict__ g1den)
{
    __shared__ float af[256];
    __shared__ float p[8][256];
    __shared__ float den8[8];
    int t = threadIdx.x;
    int b = blockIdx.x;
    int n = b >> 1, mh = b & 1;
    int mbase = mh * 256;
    af[t] = adj[n * NP + mbase + t] > 0 ? 1.0f : 0.0f;
    __syncthreads();
    #pragma unroll
    for (int r = 0; r < 8; r++) {
        int idx = r * 256 + t;
        int h = idx >> 8, m = idx & 255;
        float e = ss1[h * NP + n] + sd1[h * NP + mbase + m];
        e = fmaxf(e, NEG * e);
        p[h][m] = af[m] * __expf(e);
    }
    __syncthreads();
    int w = t >> 6, l = t & 63;
    #pragma unroll
    for (int hh = 0; hh < 2; hh++) {
        int h = w + hh * 4;
        float s = 0;
        #pragma unroll
        for (int k = 0; k < 4; k++) s += p[h][l + 64 * k];
        #pragma unroll
        for (int off = 1; off < 64; off <<= 1) s += __shfl_xor(s, off);
        if (l == 0) den8[h] = s;
    }
    __syncthreads();
    int h = t >> 5;
    float acc0 = 0.f, acc1 = 0.f;
    #pragma unroll 8
    for (int m = 0; m < 256; m += 2) {
        acc0 += p[h][m]     * hp1[(mbase + m) * 256 + t];
        acc1 += p[h][m + 1] * hp1[(mbase + m + 1) * 256 + t];
    }
    g1acc[((size_t)mh * NP + n) * 256 + t] = acc0 + acc1;
    if (t < 8) g1den[((size_t)mh * NP + n) * 8 + t] = den8[t];
}

// ---- hp2 GEMM: 64x256 A-tile in LDS, swapped MFMA (C^T), fused epilogue;
//      gat1_comb FUSED into staging for row-tiles >= NW (block-uniform branch)
// grid: b = mt(64)*8 + h(8)
__global__ __launch_bounds__(256) void k_gemm_hp2(
    const unsigned short* __restrict__ abf, const unsigned short* __restrict__ btbf,
    const float* __restrict__ wtab, const float* __restrict__ g1acc,
    const float* __restrict__ g1den, const float* __restrict__ b1,
    float* __restrict__ gpart)
{
    __shared__ unsigned short As[64][264];   // 33.8 KB
    int b = blockIdx.x;
    int h = b & 7, mt = b >> 3;
    int t = threadIdx.x;
    int w = t >> 6, l = t & 63;
    int m0 = mt * 64;
    if (m0 < NW) {
        int row = t >> 5;
        int col8 = (t & 31) * 8;
        #pragma unroll
        for (int u = 0; u < 8; u++)
            *(bf16x8*)(&As[u * 8 + row][col8]) =
                *(const bf16x8*)(abf + (size_t)(m0 + u * 8 + row) * FIN + col8);
    } else {
        // rows from GAT1: elu((a0+a1)/(d0+d1) + b1), computed during staging
        int row = t >> 5;
        int col8 = (t & 31) * 8;
        int hc = col8 >> 5;
        #pragma unroll
        for (int u = 0; u < 8; u++) {
            int n = m0 + u * 8 + row - NW;   // 0..511
            float4 a0 = *(const float4*)(g1acc + (size_t)n * 256 + col8);
            float4 a1 = *(const float4*)(g1acc + (size_t)n * 256 + col8 + 4);
            float4 c0 = *(const float4*)(g1acc + ((size_t)NP + n) * 256 + col8);
            float4 c1 = *(const float4*)(g1acc + ((size_t)NP + n) * 256 + col8 + 4);
            float dn = g1den[(size_t)n * 8 + hc] + g1den[((size_t)NP + n) * 8 + hc];
            float inv = 1.0f / dn;
            float vals[8] = {a0.x + c0.x, a0.y + c0.y, a0.z + c0.z, a0.w + c0.w,
                             a1.x + c1.x, a1.y + c1.y, a1.z + c1.z, a1.w + c1.w};
            unsigned short us[8];
            #pragma unroll
            for (int j = 0; j < 8; j++) {
                float r = vals[j] * inv + b1[(col8 & 31) + j];
                r = r > 0.f ? r : expm1f(r);
                us[j] = f2bf(r);
            }
            *(bf16x8*)(&As[u * 8 + row][col8]) = *(bf16x8*)us;
        }
    }
    __syncthreads();
    int n0 = w * 64;
    int lr = l & 15, lq = l >> 4;
    const unsigned short* bbase = btbf + h * O2 * FIN;
    f32x4 acc[4][4];
    #pragma unroll
    for (int i = 0; i < 4; i++)
        #pragma unroll
        for (int j = 0; j < 4; j++) acc[i][j] = (f32x4){0.f, 0.f, 0.f, 0.f};
    #pragma unroll
    for (int k = 0; k < FIN; k += 32) {
        bf16x8 a[4], bf[4];
        int kc = k + lq * 8;
        #pragma unroll
        for (int j = 0; j < 4; j++)
            bf[j] = *(const bf16x8*)(bbase + (size_t)(n0 + j * 16 + lr) * FIN + kc);
        #pragma unroll
        for (int i = 0; i < 4; i++)
            a[i] = *(const bf16x8*)(&As[i * 16 + lr][kc]);
        #pragma unroll
        for (int i = 0; i < 4; i++)
            #pragma unroll
            for (int j = 0; j < 4; j++)
                acc[i][j] = __builtin_amdgcn_mfma_f32_16x16x32_bf16(bf[j], a[i], acc[i][j], 0, 0, 0);
    }
    const float* wt = wtab + (size_t)h * O2 * 8;
    float* base = gpart + ((size_t)h * 4 + w) * NT * 8;
    #pragma unroll
    for (int i = 0; i < 4; i++) {
        float s[7] = {0,0,0,0,0,0,0};
        #pragma unroll
        for (int j = 0; j < 4; j++) {
            #pragma unroll
            for (int r = 0; r < 4; r++) {
                float x = acc[i][j][r];
                float ex = __expf(2.0f * x);
                float th = 1.0f - 2.0f * __builtin_amdgcn_rcpf(ex + 1.0f);  // tanh
                const float* wp = wt + (size_t)(n0 + j * 16 + lq * 4 + r) * 8;
                float4 wa = *(const float4*)wp;
                float4 wb = *(const float4*)(wp + 4);
                s[0] += th * wa.x;
                s[1] += th * wa.y;
                s[2] += x * wa.z;
                s[3] += x * wa.w;
                s[4] += x * wb.x;
                s[5] += x * wb.y;
                s[6] += x * wb.z;
            }
        }
        #pragma unroll
        for (int q = 0; q < 7; q++) {
            s[q] += __shfl_xor(s[q], 16);
            s[q] += __shfl_xor(s[q], 32);
        }
        if (lq == 0) {
            int m = m0 + i * 16 + lr;
            float* dst = base + (size_t)m * 8;
            #pragma unroll
            for (int q = 0; q < 7; q++) dst[q] = s[q];
        }
    }
}

// ---- combine slices -> Etab/Eptab + T={F,Fp,1,g0,g1,g2,g3,g4} ----
__global__ __launch_bounds__(256) void k_comb_hp2(
    const float* __restrict__ gpart,
    float* __restrict__ Etab, float* __restrict__ Eptab, float* __restrict__ T)
{
    int idx = blockIdx.x * 256 + threadIdx.x;   // h*NT + m
    float s[7] = {0,0,0,0,0,0,0};
    #pragma unroll
    for (int sl = 0; sl < 4; sl++) {
        const float* p = gpart + (((size_t)(idx >> 12) * 4 + sl) * NT + (idx & (NT - 1))) * 8;
        #pragma unroll
        for (int q = 0; q < 7; q++) s[q] += p[q];
    }
    Etab[idx]  = __expf(s[0]);
    Eptab[idx] = __expf(NEG * s[0]);
    float4 t0 = {__expf(s[1]), __expf(NEG * s[1]), 1.0f, s[2]};
    float4 t1 = {s[3], s[4], s[5], s[6]};
    *(float4*)(T + (size_t)idx * 8)     = t0;
    *(float4*)(T + (size_t)idx * 8 + 4) = t1;
}

// ---- GAT2 attention: 16 rows/wave (amortize per-q overhead), c=2, LDS masks ----
// grid: nb(56) x h(8) x c(2) = 896 blocks, 256 thr; wave owns 16 rows
// part[(((c*NW+n)*8+h)*8+s)*8 + {den,num0..4}]
__global__ __launch_bounds__(256) void k_gat2_attn(
    const unsigned* __restrict__ maskT, const float* __restrict__ Etab,
    const float* __restrict__ Eptab, const float* __restrict__ T,
    float* __restrict__ part)
{
    __shared__ unsigned pw[64 * 64];   // 16 KB: [wd(64)][row(64)]
    int t = threadIdx.x;
    int w = t >> 6, l = t & 63;
    int b = blockIdx.x;
    int nb = b % 56;
    int h  = (b / 56) & 7;
    int c  = b / 448;
    int rbase = nb * 64;
    #pragma unroll
    for (int u = 0; u < 16; u++) {
        int idx = u * 256 + t;          // 4096 words
        int wd = idx >> 6, row = idx & 63;
        pw[idx] = maskT[(size_t)(c * 64 + wd) * NW + rbase + row];
    }
    __syncthreads();
    int n0 = rbase + w * 16;
    float E[16], Ep[16];                // wave-uniform -> SGPR via readfirstlane
    #pragma unroll
    for (int i = 0; i < 16; i++) {
        int r = h * NT + n0 + i;
        E[i]  = rflf(Etab[r]);
        Ep[i] = rflf(Eptab[r]);
    }
    float den[16];
    float num[16][5];
    #pragma unroll
    for (int i = 0; i < 16; i++) {
        den[i] = 0.f;
        #pragma unroll
        for (int j = 0; j < 5; j++) num[i][j] = 0.f;
    }
    const float* Th = T + ((size_t)h * NT + c * 2048) * 8;
    int lsh = l & 31;
    int wdh = l >> 5;
    const unsigned* mb0 = pw + w * 16;
    for (int q = 0; q < 32; q++) {
        const float* tp = Th + (size_t)(q * 64 + l) * 8;
        f32x4 t0 = *(const f32x4*)tp;        // {F, Fp, 1, g0}
        f32x4 t1 = *(const f32x4*)(tp + 4);  // {g1..g4}
        const unsigned* mb = mb0 + (q * 2 + wdh) * 64;
        uint4 ma = *(const uint4*)(mb);
        uint4 mc = *(const uint4*)(mb + 4);
        uint4 me = *(const uint4*)(mb + 8);
        uint4 mg = *(const uint4*)(mb + 12);
        unsigned wv[16] = {ma.x, ma.y, ma.z, ma.w, mc.x, mc.y, mc.z, mc.w,
                           me.x, me.y, me.z, me.w, mg.x, mg.y, mg.z, mg.w};
        #pragma unroll
        for (int i = 0; i < 16; i++) {
            float bm = (float)((wv[i] >> lsh) & 1u);
            float pp = fmaxf(t0.x * E[i], t0.y * Ep[i]) * bm;
            den[i] += pp;
            num[i][0] = fmaf(pp, t0.w, num[i][0]);
            num[i][1] = fmaf(pp, t1.x, num[i][1]);
            num[i][2] = fmaf(pp, t1.y, num[i][2]);
            num[i][3] = fmaf(pp, t1.z, num[i][3]);
            num[i][4] = fmaf(pp, t1.w, num[i][4]);
        }
    }
    // 3-step butterfly -> 8 partials
    #pragma unroll
    for (int i = 0; i < 16; i++) {
        float v[6];
        v[0] = den[i];
        #pragma unroll
        for (int j = 0; j < 5; j++) v[1 + j] = num[i][j];
        #pragma unroll
        for (int off = 1; off < 8; off <<= 1)
            #pragma unroll
            for (int k = 0; k < 6; k++) v[k] += __shfl_xor(v[k], off);
        if ((l & 7) == 0) {
            float* dst = part + ((((size_t)c * NW + n0 + i) * 8 + h) * 8 + (l >> 3)) * 8;
            #pragma unroll
            for (int k = 0; k < 6; k++) dst[k] = v[k];
        }
    }
}

// ---- combine chunks(2) x partials(8) + heads -> hf[n][5] ----
__global__ __launch_bounds__(256) void k_gat2_comb(const float* __restrict__ part,
                                                   float* __restrict__ hf) {
    int idx = blockIdx.x * 256 + threadIdx.x;
    int n = idx >> 3, h = idx & 7;
    float den = 0, num[5] = {0,0,0,0,0};
    #pragma unroll
    for (int cc = 0; cc < 2; cc++) {
        #pragma unroll
        for (int s = 0; s < 8; s++) {
            const float* p = part + ((((size_t)cc * NW + n) * 8 + h) * 8 + s) * 8;
            float4 a = *(const float4*)p;
            float4 bq = *(const float4*)(p + 4);
            den += a.x;
            num[0] += a.y; num[1] += a.z; num[2] += a.w;
            num[3] += bq.x; num[4] += bq.y;
        }
    }
    float inv = 1.0f / (den * 8.0f);
    float v[5];
    #pragma unroll
    for (int j = 0; j < 5; j++) v[j] = num[j] * inv;
    #pragma unroll
    for (int off = 1; off < 8; off <<= 1)
        #pragma unroll
        for (int j = 0; j < 5; j++) v[j] += __shfl_xor(v[j], off);
    if (h == 0) {
        #pragma unroll
        for (int j = 0; j < 5; j++) hf[n * 5 + j] = v[j];
    }
}

// ---- final FC ----
__global__ __launch_bounds__(256) void k_final(
    const float* __restrict__ input, const float* __restrict__ hf,
    const float* __restrict__ cvec, const float* __restrict__ b_fc,
    float* __restrict__ out)
{
    int b = blockIdx.x, t = threadIdx.x;
    const float4* row4 = (const float4*)(input + (size_t)b * NW);
    const float4* hf4 = (const float4*)hf;
    float s = 0.f, a[5] = {0.f, 0.f, 0.f, 0.f, 0.f};
    for (int idx = t; idx < NW / 4; idx += 256) {
        float4 x = row4[idx];
        float f[20];
        #pragma unroll
        for (int q = 0; q < 5; q++) *(float4*)(f + 4 * q) = hf4[idx * 5 + q];
        s += x.x + x.y + x.z + x.w;
        #pragma unroll
        for (int j = 0; j < 5; j++)
            a[j] += x.x * f[j] + x.y * f[5 + j] + x.z * f[10 + j] + x.w * f[15 + j];
    }
    #pragma unroll
    for (int off = 1; off < 64; off <<= 1) {
        s += __shfl_xor(s, off);
        #pragma unroll
        for (int j = 0; j < 5; j++) a[j] += __shfl_xor(a[j], off);
    }
    __shared__ float red[4][6];
    int w = t >> 6, l = t & 63;
    if (l == 0) { red[w][0] = s; for (int j = 0; j < 5; j++) red[w][j + 1] = a[j]; }
    __syncthreads();
    if (t < 5) {
        float st = red[0][0] + red[1][0] + red[2][0] + red[3][0];
        float aj = red[0][t + 1] + red[1][t + 1] + red[2][t + 1] + red[3][t + 1];
        out[b * 5 + t] = aj / st + cvec[t] + b_fc[t];
    }
}

extern "C" void kernel_launch(void* const* d_in, const int* in_sizes, int n_in,
                              void* d_out, int out_size, void* d_ws, size_t ws_size,
                              hipStream_t stream) {
    const float* input   = (const float*)d_in[0];
    const float* pf      = (const float*)d_in[1];
    const float* wf      = (const float*)d_in[2];
    const float* w1      = (const float*)d_in[3];
    const float* a_src1  = (const float*)d_in[4];
    const float* a_dst1  = (const float*)d_in[5];
    const float* b1      = (const float*)d_in[6];
    const float* w2      = (const float*)d_in[7];
    const float* a_src2  = (const float*)d_in[8];
    const float* a_dst2  = (const float*)d_in[9];
    const float* b2      = (const float*)d_in[10];
    const float* W_fc    = (const float*)d_in[11];
    const float* b_fc    = (const float*)d_in[12];
    const int* pern_adj  = (const int*)d_in[13];
    const int* wp_adj    = (const int*)d_in[14];
    float* out = (float*)d_out;

    char* ws = (char*)d_ws;
    unsigned short* abf    = (unsigned short*)(ws);            // 2 MB
    unsigned short* btbf   = (unsigned short*)(ws + 2097152);  // 1 MB
    float*          hp1    = (float*)(ws + 3145728);           // 512 KB
    float*          ss1    = (float*)(ws + 3670016);           // 16 KB
    float*          sd1    = (float*)(ws + 3686400);           // 16 KB
    float*          Etab   = (float*)(ws + 3833856);           // 128 KB
    float*          Eptab  = (float*)(ws + 3964928);           // 128 KB
    float*          T      = (float*)(ws + 4096000);           // 1 MB
    float*          hf     = (float*)(ws + 5144576);           // 70 KB
    float*          cvec   = (float*)(ws + 5216256);           // 64 B
    unsigned*       maskT  = (unsigned*)(ws + 5216512);        // 1.75 MB
    float*          gpart  = (float*)(ws + 7051520);           // 4 MB -> 11245824
    float*          g1acc  = (float*)(ws + 11245824);          // 1 MB
    float*          g1den  = (float*)(ws + 12294400);          // 32 KB
    float*          part   = (float*)(ws + 12582912);          // 14.68 MB -> 27262976
    float*          wtab   = (float*)(ws + 28311552);          // 64 KB (ws >= 38 MB proven R1)

    k_prep<<<2185, 256, 0, stream>>>(wf, pf, w1, a_src1, a_dst1, w2, b2, W_fc,
                                     a_src2, a_dst2, wp_adj,
                                     abf, btbf, hp1, ss1, sd1, maskT, cvec, wtab);
    k_gat1_attn<<<1024, 256, 0, stream>>>(pern_adj, hp1, ss1, sd1, g1acc, g1den);
    k_gemm_hp2<<<512, 256, 0, stream>>>(abf, btbf, wtab, g1acc, g1den, b1, gpart);
    k_comb_hp2<<<128, 256, 0, stream>>>(gpart, Etab, Eptab, T);
    k_gat2_attn<<<896, 256, 0, stream>>>(maskT, Etab, Eptab, T, part);
    k_gat2_comb<<<112, 256, 0, stream>>>(part, hf);
    k_final<<<1024, 256, 0, stream>>>(input, hf, cvec, b_fc, out);
}

// Round 15
// 246.610 us; speedup vs baseline: 1.0460x; 1.0460x over previous
//
#include <hip/hip_runtime.h>
#include <hip/hip_bf16.h>
#include <math.h>

#define NP 512
#define NW 3584
#define NT 4096
#define FIN 256
#define H1 8
#define O1 32
#define H2 8
#define O2 256
#define NEG 0.2f

typedef __attribute__((ext_vector_type(8))) short bf16x8;
typedef __attribute__((ext_vector_type(4))) float f32x4;
typedef unsigned long long u64;

__device__ __forceinline__ unsigned short f2bf(float f) {
    unsigned u = __float_as_uint(f);
    unsigned r = (u + 0x7FFF + ((u >> 16) & 1)) >> 16;
    return (unsigned short)r;
}
__device__ __forceinline__ float rflf(float x) {
    return __uint_as_float(__builtin_amdgcn_readfirstlane(__float_as_uint(x)));
}

// ===== fused prep: conv_word | gat1_hp | conv_w2 | pack_adj(u32-T) | cvec | wtab
// grid = 896 + 256 + 128 + 896 + 1 + 8 = 2185 blocks of 256
__global__ __launch_bounds__(256) void k_prep(
    const float* __restrict__ wf, const float* __restrict__ pf,
    const float* __restrict__ w1, const float* __restrict__ a_src1,
    const float* __restrict__ a_dst1, const float* __restrict__ w2,
    const float* __restrict__ b2, const float* __restrict__ W_fc,
    const float* __restrict__ a_src2, const float* __restrict__ a_dst2,
    const int* __restrict__ wp_adj,
    unsigned short* __restrict__ abf, unsigned short* __restrict__ btbf,
    float* __restrict__ hp1, float* __restrict__ ss1, float* __restrict__ sd1,
    unsigned* __restrict__ maskT, float* __restrict__ cvec,
    float* __restrict__ wtab)
{
    __shared__ float tile[64][65];
    __shared__ float feat[2][FIN];
    __shared__ float red[4][5];
    int blk = blockIdx.x;
    int t = threadIdx.x;
    if (blk < 896) {
        int idx4 = blk * 256 + t;
        float4 x = ((const float4*)wf)[idx4];
        ushort4 y;
        y.x = f2bf(x.x); y.y = f2bf(x.y); y.z = f2bf(x.z); y.w = f2bf(x.w);
        ((ushort4*)abf)[idx4] = y;
    } else if (blk < 1152) {
        int n0 = (blk - 896) * 2;
        feat[0][t] = pf[n0 * FIN + t];
        feat[1][t] = pf[(n0 + 1) * FIN + t];
        __syncthreads();
        int h = t >> 5, o = t & 31;
        float acc0 = 0.f, acc1 = 0.f;
        const float* wcol = w1 + h * FIN * O1 + o;
        #pragma unroll 4
        for (int f = 0; f < FIN; f++) {
            float w = wcol[f * O1];
            acc0 += feat[0][f] * w;
            acc1 += feat[1][f] * w;
        }
        hp1[n0 * 256 + t] = acc0;
        hp1[(n0 + 1) * 256 + t] = acc1;
        float as = a_src1[h * O1 + o];
        float ad = a_dst1[h * O1 + o];
        float accs[2] = {acc0, acc1};
        #pragma unroll
        for (int i = 0; i < 2; i++) {
            float th = tanhf(accs[i]);
            float vs = th * as, vd = th * ad;
            #pragma unroll
            for (int off = 1; off < 32; off <<= 1) {
                vs += __shfl_xor(vs, off);
                vd += __shfl_xor(vd, off);
            }
            if (o == 0) { ss1[h * NP + n0 + i] = vs; sd1[h * NP + n0 + i] = vd; }
        }
    } else if (blk < 1280) {
        int blk2 = blk - 1152;
        int h = blk2 >> 4;
        int f0 = ((blk2 >> 2) & 3) * 64;
        int o0 = (blk2 & 3) * 64;
        #pragma unroll
        for (int rr = 0; rr < 16; rr++) {
            int f = rr * 4 + (t >> 6);
            int o = t & 63;
            tile[f][o] = w2[((size_t)(h * FIN + f0 + f)) * O2 + o0 + o];
        }
        __syncthreads();
        #pragma unroll
        for (int rr = 0; rr < 16; rr++) {
            int o = rr * 4 + (t >> 6);
            int f = t & 63;
            btbf[((size_t)(h * O2 + o0 + o)) * FIN + f0 + f] = f2bf(tile[f][o]);
        }
    } else if (blk < 2176) {
        // pack_adj -> u32 transposed: maskT[word(128)][row(3584)]
        int w = t >> 6, l = t & 63;
        int r = (blk - 1280) * 4 + w;
        const int4* row = (const int4*)(wp_adj + (size_t)r * NT);
        for (int c4 = 0; c4 < 16; c4++) {
            int4 x = row[c4 * 64 + l];
            u64 nib = (u64)((x.x != 0 ? 1 : 0) | (x.y != 0 ? 2 : 0) |
                            (x.z != 0 ? 4 : 0) | (x.w != 0 ? 8 : 0));
            u64 v = nib << (4 * (l & 15));
            v |= __shfl_xor(v, 1);
            v |= __shfl_xor(v, 2);
            v |= __shfl_xor(v, 4);
            v |= __shfl_xor(v, 8);
            if ((l & 15) == 0) {
                int qw = c4 * 4 + (l >> 4);
                maskT[(size_t)(2 * qw) * NW + r]     = (unsigned)v;
                maskT[(size_t)(2 * qw + 1) * NW + r] = (unsigned)(v >> 32);
            }
        }
    } else if (blk == 2176) {
        float v[5];
        #pragma unroll
        for (int j = 0; j < 5; j++) v[j] = b2[t] * W_fc[t * 5 + j];
        #pragma unroll
        for (int off = 1; off < 64; off <<= 1)
            #pragma unroll
            for (int j = 0; j < 5; j++) v[j] += __shfl_xor(v[j], off);
        int w = t >> 6, l = t & 63;
        if (l == 0) { for (int j = 0; j < 5; j++) red[w][j] = v[j]; }
        __syncthreads();
        if (t == 0)
            for (int j = 0; j < 5; j++) cvec[j] = red[0][j] + red[1][j] + red[2][j] + red[3][j];
    } else {
        int h = blk - 2177;
        int o = t;
        float* dst = wtab + ((size_t)h * O2 + o) * 8;
        float4 d0 = {a_src2[h * O2 + o], a_dst2[h * O2 + o], W_fc[o * 5], W_fc[o * 5 + 1]};
        float4 d1 = {W_fc[o * 5 + 2], W_fc[o * 5 + 3], W_fc[o * 5 + 4], 0.f};
        *(float4*)dst = d0;
        *(float4*)(dst + 4) = d1;
    }
}

// ---- GAT1 attention: m-split x2 -> grid 1024 (n x mh), partial den/acc out ----
__global__ __launch_bounds__(256) void k_gat1_attn(
    const int* __restrict__ adj, const float* __restrict__ hp1,
    const float* __restrict__ ss1, const float* __restrict__ sd1,
    float* __restrict__ g1acc, float* __restrict__ g1den)
{
    __shared__ float af[256];
    __shared__ float p[8][256];
    __shared__ float den8[8];
    int t = threadIdx.x;
    int b = blockIdx.x;
    int n = b >> 1, mh = b & 1;
    int mbase = mh * 256;
    af[t] = adj[n * NP + mbase + t] > 0 ? 1.0f : 0.0f;
    __syncthreads();
    #pragma unroll
    for (int r = 0; r < 8; r++) {
        int idx = r * 256 + t;
        int h = idx >> 8, m = idx & 255;
        float e = ss1[h * NP + n] + sd1[h * NP + mbase + m];
        e = fmaxf(e, NEG * e);
        p[h][m] = af[m] * __expf(e);
    }
    __syncthreads();
    int w = t >> 6, l = t & 63;
    #pragma unroll
    for (int hh = 0; hh < 2; hh++) {
        int h = w + hh * 4;
        float s = 0;
        #pragma unroll
        for (int k = 0; k < 4; k++) s += p[h][l + 64 * k];
        #pragma unroll
        for (int off = 1; off < 64; off <<= 1) s += __shfl_xor(s, off);
        if (l == 0) den8[h] = s;
    }
    __syncthreads();
    int h = t >> 5;
    float acc0 = 0.f, acc1 = 0.f;
    #pragma unroll 8
    for (int m = 0; m < 256; m += 2) {
        acc0 += p[h][m]     * hp1[(mbase + m) * 256 + t];
        acc1 += p[h][m + 1] * hp1[(mbase + m + 1) * 256 + t];
    }
    g1acc[((size_t)mh * NP + n) * 256 + t] = acc0 + acc1;
    if (t < 8) g1den[((size_t)mh * NP + n) * 8 + t] = den8[t];
}

// ---- hp2 GEMM: 32x256 A-tile (16.9 KB LDS), grid 1024 (4 blocks/CU), swapped MFMA,
//      fused epilogue + fused comb (Etab/Eptab/T written directly), gat1 rows fused
// grid: b = mt(128)*8 + h(8)
__global__ __launch_bounds__(256) void k_gemm_hp2(
    const unsigned short* __restrict__ abf, const unsigned short* __restrict__ btbf,
    const float* __restrict__ wtab, const float* __restrict__ g1acc,
    const float* __restrict__ g1den, const float* __restrict__ b1,
    float* __restrict__ Etab, float* __restrict__ Eptab, float* __restrict__ T)
{
    __shared__ unsigned short As[32][264];   // 16.9 KB
    __shared__ float sred[4][32][8];         // 4 KB
    int b = blockIdx.x;
    int h = b & 7, mt = b >> 3;
    int t = threadIdx.x;
    int w = t >> 6, l = t & 63;
    int m0 = mt * 32;
    if (m0 < NW) {
        int row = t >> 5;
        int col8 = (t & 31) * 8;
        #pragma unroll
        for (int u = 0; u < 4; u++)
            *(bf16x8*)(&As[u * 8 + row][col8]) =
                *(const bf16x8*)(abf + (size_t)(m0 + u * 8 + row) * FIN + col8);
    } else {
        // rows from GAT1: elu((a0+a1)/(d0+d1) + b1), computed during staging
        int row = t >> 5;
        int col8 = (t & 31) * 8;
        int hc = col8 >> 5;
        #pragma unroll
        for (int u = 0; u < 4; u++) {
            int n = m0 + u * 8 + row - NW;   // 0..511
            float4 a0 = *(const float4*)(g1acc + (size_t)n * 256 + col8);
            float4 a1 = *(const float4*)(g1acc + (size_t)n * 256 + col8 + 4);
            float4 c0 = *(const float4*)(g1acc + ((size_t)NP + n) * 256 + col8);
            float4 c1 = *(const float4*)(g1acc + ((size_t)NP + n) * 256 + col8 + 4);
            float dn = g1den[(size_t)n * 8 + hc] + g1den[((size_t)NP + n) * 8 + hc];
            float inv = 1.0f / dn;
            float vals[8] = {a0.x + c0.x, a0.y + c0.y, a0.z + c0.z, a0.w + c0.w,
                             a1.x + c1.x, a1.y + c1.y, a1.z + c1.z, a1.w + c1.w};
            unsigned short us[8];
            #pragma unroll
            for (int j = 0; j < 8; j++) {
                float r = vals[j] * inv + b1[(col8 & 31) + j];
                r = r > 0.f ? r : expm1f(r);
                us[j] = f2bf(r);
            }
            *(bf16x8*)(&As[u * 8 + row][col8]) = *(bf16x8*)us;
        }
    }
    __syncthreads();
    int n0 = w * 64;
    int lr = l & 15, lq = l >> 4;
    const unsigned short* bbase = btbf + h * O2 * FIN;
    f32x4 acc[2][4];
    #pragma unroll
    for (int i = 0; i < 2; i++)
        #pragma unroll
        for (int j = 0; j < 4; j++) acc[i][j] = (f32x4){0.f, 0.f, 0.f, 0.f};
    #pragma unroll
    for (int k = 0; k < FIN; k += 32) {
        bf16x8 a[2], bf[4];
        int kc = k + lq * 8;
        #pragma unroll
        for (int j = 0; j < 4; j++)
            bf[j] = *(const bf16x8*)(bbase + (size_t)(n0 + j * 16 + lr) * FIN + kc);
        #pragma unroll
        for (int i = 0; i < 2; i++)
            a[i] = *(const bf16x8*)(&As[i * 16 + lr][kc]);
        // swapped operands: D[o][m] — lane holds m = lr, o = n0 + j*16 + lq*4 + r
        #pragma unroll
        for (int i = 0; i < 2; i++)
            #pragma unroll
            for (int j = 0; j < 4; j++)
                acc[i][j] = __builtin_amdgcn_mfma_f32_16x16x32_bf16(bf[j], a[i], acc[i][j], 0, 0, 0);
    }
    const float* wt = wtab + (size_t)h * O2 * 8;
    #pragma unroll
    for (int i = 0; i < 2; i++) {
        float s[7] = {0,0,0,0,0,0,0};
        #pragma unroll
        for (int j = 0; j < 4; j++) {
            #pragma unroll
            for (int r = 0; r < 4; r++) {
                float x = acc[i][j][r];
                float ex = __expf(2.0f * x);
                float th = 1.0f - 2.0f * __builtin_amdgcn_rcpf(ex + 1.0f);  // tanh
                const float* wp = wt + (size_t)(n0 + j * 16 + lq * 4 + r) * 8;
                float4 wa = *(const float4*)wp;
                float4 wb = *(const float4*)(wp + 4);
                s[0] += th * wa.x;
                s[1] += th * wa.y;
                s[2] += x * wa.z;
                s[3] += x * wa.w;
                s[4] += x * wb.x;
                s[5] += x * wb.y;
                s[6] += x * wb.z;
            }
        }
        #pragma unroll
        for (int q = 0; q < 7; q++) {
            s[q] += __shfl_xor(s[q], 16);
            s[q] += __shfl_xor(s[q], 32);
        }
        if (lq == 0) {
            #pragma unroll
            for (int q = 0; q < 7; q++) sred[w][i * 16 + lr][q] = s[q];
        }
    }
    __syncthreads();
    // fused comb: sum the 4 o-slices, write Etab/Eptab/T
    if (t < 32) {
        float s[7];
        #pragma unroll
        for (int q = 0; q < 7; q++)
            s[q] = sred[0][t][q] + sred[1][t][q] + sred[2][t][q] + sred[3][t][q];
        int idx = h * NT + m0 + t;
        Etab[idx]  = __expf(s[0]);
        Eptab[idx] = __expf(NEG * s[0]);
        float4 t0 = {__expf(s[1]), __expf(NEG * s[1]), 1.0f, s[2]};
        float4 t1 = {s[3], s[4], s[5], s[6]};
        *(float4*)(T + (size_t)idx * 8)     = t0;
        *(float4*)(T + (size_t)idx * 8 + 4) = t1;
    }
}

// ---- GAT2 attention: R12 config — 8 rows/wave, c=2, LDS u32 masks, asm-free ----
// grid: nb(112, 32 rows) x h(8) x c(2) = 1792 blocks, 256 thr
__global__ __launch_bounds__(256) void k_gat2_attn(
    const unsigned* __restrict__ maskT, const float* __restrict__ Etab,
    const float* __restrict__ Eptab, const float* __restrict__ T,
    float* __restrict__ part)
{
    __shared__ unsigned pw[64 * 32];   // 8 KB: [wd(64)][row(32)]
    int t = threadIdx.x;
    int w = t >> 6, l = t & 63;
    int b = blockIdx.x;
    int nb = b % 112;
    int h  = (b / 112) & 7;
    int c  = b / 896;
    int rbase = nb * 32;
    #pragma unroll
    for (int u = 0; u < 8; u++) {
        int idx = u * 256 + t;          // 2048 words
        int wd = idx >> 5, row = idx & 31;
        pw[idx] = maskT[(size_t)(c * 64 + wd) * NW + rbase + row];
    }
    __syncthreads();
    int n0 = rbase + w * 8;
    float E[8], Ep[8];
    #pragma unroll
    for (int i = 0; i < 8; i++) {
        int r = h * NT + n0 + i;
        E[i]  = rflf(Etab[r]);
        Ep[i] = rflf(Eptab[r]);
    }
    float den[8] = {0,0,0,0,0,0,0,0};
    float num[8][5] = {{0}};
    const float* Th = T + ((size_t)h * NT + c * 2048) * 8;
    int lsh = l & 31;
    int wdh = l >> 5;
    const unsigned* mbase = pw + w * 8;
    for (int q = 0; q < 32; q++) {
        const float* tp = Th + (size_t)(q * 64 + l) * 8;
        f32x4 t0 = *(const f32x4*)tp;        // {F, Fp, 1, g0}
        f32x4 t1 = *(const f32x4*)(tp + 4);  // {g1..g4}
        int wd = q * 2 + wdh;
        uint4 ma = *(const uint4*)(mbase + wd * 32);       // rows 0..3
        uint4 mb = *(const uint4*)(mbase + wd * 32 + 4);   // rows 4..7
        unsigned wv[8] = {ma.x, ma.y, ma.z, ma.w, mb.x, mb.y, mb.z, mb.w};
        #pragma unroll
        for (int i = 0; i < 8; i++) {
            float bm = (float)((wv[i] >> lsh) & 1u);
            float pa = t0.x * E[i];
            float pb = t0.y * Ep[i];
            float pp = fmaxf(pa, pb) * bm;   // exp(leaky(ss+sd)) * adj
            den[i] += pp;
            num[i][0] = fmaf(pp, t0.w, num[i][0]);
            num[i][1] = fmaf(pp, t1.x, num[i][1]);
            num[i][2] = fmaf(pp, t1.y, num[i][2]);
            num[i][3] = fmaf(pp, t1.z, num[i][3]);
            num[i][4] = fmaf(pp, t1.w, num[i][4]);
        }
    }
    #pragma unroll
    for (int i = 0; i < 8; i++) {
        float v[6];
        v[0] = den[i];
        #pragma unroll
        for (int j = 0; j < 5; j++) v[1 + j] = num[i][j];
        #pragma unroll
        for (int off = 1; off < 8; off <<= 1)
            #pragma unroll
            for (int k = 0; k < 6; k++) v[k] += __shfl_xor(v[k], off);
        if ((l & 7) == 0) {
            float* dst = part + ((((size_t)c * NW + n0 + i) * 8 + h) * 8 + (l >> 3)) * 8;
            #pragma unroll
            for (int k = 0; k < 6; k++) dst[k] = v[k];
        }
    }
}

// ---- combine chunks(2) x partials(8) + heads -> hf[n][5] ----
__global__ __launch_bounds__(256) void k_gat2_comb(const float* __restrict__ part,
                                                   float* __restrict__ hf) {
    int idx = blockIdx.x * 256 + threadIdx.x;
    int n = idx >> 3, h = idx & 7;
    float den = 0, num[5] = {0,0,0,0,0};
    #pragma unroll
    for (int cc = 0; cc < 2; cc++) {
        #pragma unroll
        for (int s = 0; s < 8; s++) {
            const float* p = part + ((((size_t)cc * NW + n) * 8 + h) * 8 + s) * 8;
            float4 a = *(const float4*)p;
            float4 bq = *(const float4*)(p + 4);
            den += a.x;
            num[0] += a.y; num[1] += a.z; num[2] += a.w;
            num[3] += bq.x; num[4] += bq.y;
        }
    }
    float inv = 1.0f / (den * 8.0f);
    float v[5];
    #pragma unroll
    for (int j = 0; j < 5; j++) v[j] = num[j] * inv;
    #pragma unroll
    for (int off = 1; off < 8; off <<= 1)
        #pragma unroll
        for (int j = 0; j < 5; j++) v[j] += __shfl_xor(v[j], off);
    if (h == 0) {
        #pragma unroll
        for (int j = 0; j < 5; j++) hf[n * 5 + j] = v[j];
    }
}

// ---- final FC ----
__global__ __launch_bounds__(256) void k_final(
    const float* __restrict__ input, const float* __restrict__ hf,
    const float* __restrict__ cvec, const float* __restrict__ b_fc,
    float* __restrict__ out)
{
    int b = blockIdx.x, t = threadIdx.x;
    const float4* row4 = (const float4*)(input + (size_t)b * NW);
    const float4* hf4 = (const float4*)hf;
    float s = 0.f, a[5] = {0.f, 0.f, 0.f, 0.f, 0.f};
    for (int idx = t; idx < NW / 4; idx += 256) {
        float4 x = row4[idx];
        float f[20];
        #pragma unroll
        for (int q = 0; q < 5; q++) *(float4*)(f + 4 * q) = hf4[idx * 5 + q];
        s += x.x + x.y + x.z + x.w;
        #pragma unroll
        for (int j = 0; j < 5; j++)
            a[j] += x.x * f[j] + x.y * f[5 + j] + x.z * f[10 + j] + x.w * f[15 + j];
    }
    #pragma unroll
    for (int off = 1; off < 64; off <<= 1) {
        s += __shfl_xor(s, off);
        #pragma unroll
        for (int j = 0; j < 5; j++) a[j] += __shfl_xor(a[j], off);
    }
    __shared__ float red[4][6];
    int w = t >> 6, l = t & 63;
    if (l == 0) { red[w][0] = s; for (int j = 0; j < 5; j++) red[w][j + 1] = a[j]; }
    __syncthreads();
    if (t < 5) {
        float st = red[0][0] + red[1][0] + red[2][0] + red[3][0];
        float aj = red[0][t + 1] + red[1][t + 1] + red[2][t + 1] + red[3][t + 1];
        out[b * 5 + t] = aj / st + cvec[t] + b_fc[t];
    }
}

extern "C" void kernel_launch(void* const* d_in, const int* in_sizes, int n_in,
                              void* d_out, int out_size, void* d_ws, size_t ws_size,
                              hipStream_t stream) {
    const float* input   = (const float*)d_in[0];
    const float* pf      = (const float*)d_in[1];
    const float* wf      = (const float*)d_in[2];
    const float* w1      = (const float*)d_in[3];
    const float* a_src1  = (const float*)d_in[4];
    const float* a_dst1  = (const float*)d_in[5];
    const float* b1      = (const float*)d_in[6];
    const float* w2      = (const float*)d_in[7];
    const float* a_src2  = (const float*)d_in[8];
    const float* a_dst2  = (const float*)d_in[9];
    const float* b2      = (const float*)d_in[10];
    const float* W_fc    = (const float*)d_in[11];
    const float* b_fc    = (const float*)d_in[12];
    const int* pern_adj  = (const int*)d_in[13];
    const int* wp_adj    = (const int*)d_in[14];
    float* out = (float*)d_out;

    char* ws = (char*)d_ws;
    unsigned short* abf    = (unsigned short*)(ws);            // 2 MB
    unsigned short* btbf   = (unsigned short*)(ws + 2097152);  // 1 MB
    float*          hp1    = (float*)(ws + 3145728);           // 512 KB
    float*          ss1    = (float*)(ws + 3670016);           // 16 KB
    float*          sd1    = (float*)(ws + 3686400);           // 16 KB
    float*          Etab   = (float*)(ws + 3833856);           // 128 KB
    float*          Eptab  = (float*)(ws + 3964928);           // 128 KB
    float*          T      = (float*)(ws + 4096000);           // 1 MB
    float*          hf     = (float*)(ws + 5144576);           // 70 KB
    float*          cvec   = (float*)(ws + 5216256);           // 64 B
    unsigned*       maskT  = (unsigned*)(ws + 5216512);        // 1.75 MB
    float*          g1acc  = (float*)(ws + 11245824);          // 1 MB
    float*          g1den  = (float*)(ws + 12294400);          // 32 KB
    float*          part   = (float*)(ws + 12582912);          // 14.68 MB -> 27983872
    float*          wtab   = (float*)(ws + 28311552);          // 64 KB (ws >= 38 MB proven R1)

    k_prep<<<2185, 256, 0, stream>>>(wf, pf, w1, a_src1, a_dst1, w2, b2, W_fc,
                                     a_src2, a_dst2, wp_adj,
                                     abf, btbf, hp1, ss1, sd1, maskT, cvec, wtab);
    k_gat1_attn<<<1024, 256, 0, stream>>>(pern_adj, hp1, ss1, sd1, g1acc, g1den);
    k_gemm_hp2<<<1024, 256, 0, stream>>>(abf, btbf, wtab, g1acc, g1den, b1,
                                         Etab, Eptab, T);
    k_gat2_attn<<<1792, 256, 0, stream>>>(maskT, Etab, Eptab, T, part);
    k_gat2_comb<<<112, 256, 0, stream>>>(part, hf);
    k_final<<<1024, 256, 0, stream>>>(input, hf, cvec, b_fc, out);
}